// Round 1
// 472.950 us; speedup vs baseline: 1.3079x; 1.3079x over previous
//
#include <hip/hip_runtime.h>
#include <hip/hip_bf16.h>

typedef __bf16 bf16;
typedef __bf16 bf16x4 __attribute__((ext_vector_type(4)));
typedef __bf16 bf16x8 __attribute__((ext_vector_type(8)));
typedef float  floatx4 __attribute__((ext_vector_type(4)));

#define NUM_NODES 2000000
#define NUM_DAGS  20000
#define NE 32

#define MFMA(a, b, c) __builtin_amdgcn_mfma_f32_16x16x32_bf16((a), (b), (c), 0, 0, 0)

#define ROW_BYTES  144                 // 16 nodes/tile, 144 B per node-row
#define TILE_BYTES (16 * ROW_BYTES)    // 2304 B
#define WAVE_LDS   (4 * TILE_BYTES)    // 9216 B: one 64-node group per wave
#define WCHUNK     512                 // nodes per wave (contiguous)
#define NGROUPS    (WCHUNK / 64)       // 8 groups of 64 nodes
#define CHUNK      (4 * WCHUNK)        // 2048 nodes per block

// Find largest s in [0, NUM_DAGS-1] with ptr[s*st] <= n.
// st = 1 for int32 ptr, 2 for int64 (little-endian low words).
__device__ __forceinline__ int seg_of(const int* __restrict__ ptr, int n, int st) {
    int lo = 0, hi = NUM_DAGS;
    while (hi - lo > 1) {
        int mid = (lo + hi) >> 1;
        if (ptr[mid * st] <= n) lo = mid; else hi = mid;
    }
    return lo;
}

// Load activation B-fragments for one 64-node group starting at gBase.
// A0: h_node k=0..31 frag; A1: x/bias k=32..63 frag (only q==0 lanes non-zero).
#define LOADG(gBase, A0, A1)                                                      \
    do {                                                                          \
        _Pragma("unroll")                                                         \
        for (int j_ = 0; j_ < 4; ++j_) {                                          \
            const int node_ = (gBase) + j_ * 16 + mr;                             \
            bf16x8 f_ = {};                                                       \
            bf16x8 g_ = {};                                                       \
            if (node_ < NUM_NODES) {                                              \
                const floatx4* hp_ =                                              \
                    (const floatx4*)(h_node + (size_t)node_ * 32 + q * 8);        \
                floatx4 v0_ = hp_[0], v1_ = hp_[1];                               \
                f_[0] = (bf16)v0_[0]; f_[1] = (bf16)v0_[1];                       \
                f_[2] = (bf16)v0_[2]; f_[3] = (bf16)v0_[3];                       \
                f_[4] = (bf16)v1_[0]; f_[5] = (bf16)v1_[1];                       \
                f_[6] = (bf16)v1_[2]; f_[7] = (bf16)v1_[3];                       \
                if (q == 0) {                                                     \
                    const float* xp_ = x + (size_t)node_ * 5;                     \
                    g_[0] = (bf16)xp_[0]; g_[1] = (bf16)xp_[1];                   \
                    g_[2] = (bf16)xp_[2]; g_[3] = (bf16)xp_[3];                   \
                    g_[4] = (bf16)xp_[4];                                         \
                    g_[5] = (bf16)1.0f;   /* bias-1 slot (k=37) */                \
                }                                                                 \
            }                                                                     \
            A0[j_] = f_;                                                          \
            A1[j_] = g_;                                                          \
        }                                                                         \
    } while (0)

// Persistent-chunk version: each block owns CHUNK contiguous nodes, each wave a
// contiguous WCHUNK sub-range. Weights are loaded ONCE per block (8x amortized
// vs the old 256-nodes-per-block kernel). All LDS is wave-private => no
// __syncthreads anywhere; waves are fully decoupled. Next group's activation
// fragments are prefetched into registers before the current group's MFMAs.
__global__ __launch_bounds__(256, 2)
void dag_mfma_kernel(const float* __restrict__ h_node,
                     const float* __restrict__ x,
                     const float* __restrict__ W1, const float* __restrict__ b1,
                     const float* __restrict__ W2, const float* __restrict__ b2,
                     const float* __restrict__ W3, const float* __restrict__ b3,
                     const int* __restrict__ ptr,
                     float* __restrict__ out) {
    __shared__ __align__(16) char sBuf[16 * TILE_BYTES];   // 36,864 B (4 waves)

    const int tid = threadIdx.x;
    const int w   = tid >> 6;
    const int l   = tid & 63;
    const int q   = l >> 4;
    const int mr  = l & 15;

    const int wStart = blockIdx.x * CHUNK + w * WCHUNK;
    if (wStart >= NUM_NODES) return;          // safe: no barriers in this kernel

    const int pstride = (ptr[NUM_DAGS] == NUM_NODES) ? 1 : 2;

    // ---- issue group-0 activation loads first (start HBM fetch early) ----
    bf16x8 a0c[4], a1c[4];
    bf16x8 a0n[4] = {}, a1n[4] = {};
    LOADG(wStart, a0c, a1c);

    // ---- weight A-fragments (once per block; L2-resident) ----
    bf16x8 w1f[2][4], w2f[2][4], w3f[2][2];
    #pragma unroll
    for (int s = 0; s < 2; ++s) {
        #pragma unroll
        for (int mt = 0; mt < 4; ++mt) {
            #pragma unroll
            for (int j = 0; j < 8; ++j) {
                const int kk  = s * 32 + q * 8 + j;
                const int col = mt * 16 + mr;
                float v1;
                if      (kk < 32)  v1 = W1[(kk + 5) * 64 + col];
                else if (kk < 37)  v1 = W1[(kk - 32) * 64 + col];
                else if (kk == 37) v1 = b1[col];
                else               v1 = 0.0f;
                w1f[s][mt][j] = (bf16)v1;
                w2f[s][mt][j] = (bf16)W2[kk * 64 + col];
                if (mt < 2) w3f[s][mt][j] = (bf16)W3[kk * 32 + mt * 16 + mr];
            }
        }
    }
    floatx4 b2f[4], b3f[2];
    #pragma unroll
    for (int mt = 0; mt < 4; ++mt)
        b2f[mt] = *(const floatx4*)(b2 + mt * 16 + q * 4);
    b3f[0] = *(const floatx4*)(b3 + q * 4);
    b3f[1] = *(const floatx4*)(b3 + 16 + q * 4);

    // one binary search per wave; tracked incrementally afterwards
    int seg = seg_of(ptr, wStart, pstride);

    char* myBuf = sBuf + w * WAVE_LDS;

    for (int g = 0; g < NGROUPS; ++g) {
        const int gLo = wStart + g * 64;
        if (gLo >= NUM_NODES) break;

        // prefetch next group's activations (hidden under the MFMA phases)
        if (g + 1 < NGROUPS) LOADG(gLo + 64, a0n, a1n);

        // ---- phase A: layer 1 (reg frags -> relu -> LDS) ----
        #pragma unroll
        for (int j = 0; j < 4; ++j) {
            floatx4 c[4] = {};
            #pragma unroll
            for (int mt = 0; mt < 4; ++mt) {
                c[mt] = MFMA(w1f[0][mt], a0c[j], c[mt]);
                c[mt] = MFMA(w1f[1][mt], a1c[j], c[mt]);
            }
            char* tb = myBuf + j * TILE_BYTES + mr * ROW_BYTES;
            #pragma unroll
            for (int mt = 0; mt < 4; ++mt) {
                bf16x4 v;
                v[0] = (bf16)fmaxf(c[mt][0], 0.0f);
                v[1] = (bf16)fmaxf(c[mt][1], 0.0f);
                v[2] = (bf16)fmaxf(c[mt][2], 0.0f);
                v[3] = (bf16)fmaxf(c[mt][3], 0.0f);
                *(bf16x4*)(tb + mt * 32 + q * 8) = v;   // feats mt*16+q*4.. of node mr
            }
        }

        // ---- phase B: layer 2 (LDS -> relu -> LDS in place; DS in-order/wave) ----
        #pragma unroll
        for (int j = 0; j < 4; ++j) {
            char* tb = myBuf + j * TILE_BYTES + mr * ROW_BYTES;
            bf16x8 h0 = *(const bf16x8*)(tb + q * 16);        // feats q*8..+7
            bf16x8 h1 = *(const bf16x8*)(tb + 64 + q * 16);   // feats 32+q*8..+7
            floatx4 c[4];
            #pragma unroll
            for (int mt = 0; mt < 4; ++mt) {
                c[mt] = b2f[mt];
                c[mt] = MFMA(w2f[0][mt], h0, c[mt]);
                c[mt] = MFMA(w2f[1][mt], h1, c[mt]);
            }
            #pragma unroll
            for (int mt = 0; mt < 4; ++mt) {
                bf16x4 v;
                v[0] = (bf16)fmaxf(c[mt][0], 0.0f);
                v[1] = (bf16)fmaxf(c[mt][1], 0.0f);
                v[2] = (bf16)fmaxf(c[mt][2], 0.0f);
                v[3] = (bf16)fmaxf(c[mt][3], 0.0f);
                *(bf16x4*)(tb + mt * 32 + q * 8) = v;
            }
        }

        // ---- phase C: layer 3 (LDS -> fp32 out tile, aliases bf16 buffer) ----
        #pragma unroll
        for (int j = 0; j < 4; ++j) {
            char* tb = myBuf + j * TILE_BYTES + mr * ROW_BYTES;
            bf16x8 p0 = *(const bf16x8*)(tb + q * 16);
            bf16x8 p1 = *(const bf16x8*)(tb + 64 + q * 16);
            floatx4 d0 = b3f[0], d1 = b3f[1];
            d0 = MFMA(w3f[0][0], p0, d0);
            d0 = MFMA(w3f[1][0], p1, d0);
            d1 = MFMA(w3f[0][1], p0, d1);
            d1 = MFMA(w3f[1][1], p1, d1);
            *(floatx4*)(tb + q * 16)      = d0;   // fp32 feats q*4..+3   of node mr
            *(floatx4*)(tb + 64 + q * 16) = d1;   // fp32 feats 16+q*4..+3
        }

        // ---- epilogue: per-wave segment-sum over this group's 64 nodes ----
        {
            const int gEnd = (gLo + 64 < NUM_NODES) ? gLo + 64 : NUM_NODES;
            // incremental advance (avg <1 step; terminates via ptr[NUM_DAGS]=N)
            while (ptr[(seg + 1) * pstride] <= gLo) ++seg;
            int segLast = seg;
            while (ptr[(segLast + 1) * pstride] <= gEnd - 1) ++segLast;

            const int f  = l & 31;        // feature
            const int gg = l >> 5;        // segment group 0..1
            const float* so = (const float*)myBuf;
            for (int s = seg + gg; s <= segLast; s += 2) {
                int lo = ptr[s * pstride];
                int hi = ptr[(s + 1) * pstride];
                if (lo < gLo) lo = gLo;
                if (hi > gEnd) hi = gEnd;
                float acc = 0.0f;
                for (int i = lo; i < hi; ++i) {
                    const int nl = i - gLo;
                    acc += so[(nl >> 4) * 576 + (nl & 15) * 36 + f];
                }
                if (hi > lo) atomicAdd(&out[s * NE + f], acc);
            }
            seg = segLast;
        }

        // rotate prefetch buffers (static indices; becomes register renames)
        #pragma unroll
        for (int j = 0; j < 4; ++j) { a0c[j] = a0n[j]; a1c[j] = a1n[j]; }
    }
}

extern "C" void kernel_launch(void* const* d_in, const int* in_sizes, int n_in,
                              void* d_out, int out_size, void* d_ws, size_t ws_size,
                              hipStream_t stream) {
    const float* h_node = (const float*)d_in[0];
    const float* x      = (const float*)d_in[1];
    const float* W1     = (const float*)d_in[2];
    const float* b1     = (const float*)d_in[3];
    const float* W2     = (const float*)d_in[4];
    const float* b2     = (const float*)d_in[5];
    const float* W3     = (const float*)d_in[6];
    const float* b3     = (const float*)d_in[7];
    const int*   ptr    = (const int*)d_in[8];
    float* out          = (float*)d_out;

    hipMemsetAsync(out, 0, (size_t)out_size * sizeof(float), stream);

    const int grid = (NUM_NODES + CHUNK - 1) / CHUNK;   // 977 blocks, 2048 nodes each
    dag_mfma_kernel<<<grid, 256, 0, stream>>>(h_node, x, W1, b1, W2, b2,
                                              W3, b3, ptr, out);
}

// Round 4
// 451.726 us; speedup vs baseline: 1.3693x; 1.0470x over previous
//
#include <hip/hip_runtime.h>
#include <hip/hip_bf16.h>

typedef __bf16 bf16;
typedef __bf16 bf16x4 __attribute__((ext_vector_type(4)));
typedef __bf16 bf16x8 __attribute__((ext_vector_type(8)));
typedef float  floatx4 __attribute__((ext_vector_type(4)));

#define NUM_NODES 2000000
#define NUM_DAGS  20000
#define NE 32

#define MFMA(a, b, c) __builtin_amdgcn_mfma_f32_16x16x32_bf16((a), (b), (c), 0, 0, 0)

#define ROW_BYTES  144                 // 16 nodes/tile, 144 B per node-row
#define TILE_BYTES (16 * ROW_BYTES)    // 2304 B
#define WAVE_LDS   (4 * TILE_BYTES)    // 9216 B: one 64-node group per wave
#define WCHUNK     512                 // nodes per wave (contiguous)
#define NGROUPS    (WCHUNK / 64)       // 8 groups of 64 nodes
#define CHUNK      (4 * WCHUNK)        // 2048 nodes per block

// Find largest s in [0, NUM_DAGS-1] with ptr[s*st] <= n.
// st = 1 for int32 ptr, 2 for int64 (little-endian low words).
__device__ __forceinline__ int seg_of(const int* __restrict__ ptr, int n, int st) {
    int lo = 0, hi = NUM_DAGS;
    while (hi - lo > 1) {
        int mid = (lo + hi) >> 1;
        if (ptr[mid * st] <= n) lo = mid; else hi = mid;
    }
    return lo;
}

// Load activation B-fragments for one 64-node group starting at gBase.
// A0: h_node k=0..31 frag; A1: x/bias k=32..63 frag (only q==0 lanes non-zero).
#define LOADG(gBase, A0, A1)                                                      \
    do {                                                                          \
        _Pragma("unroll")                                                         \
        for (int j_ = 0; j_ < 4; ++j_) {                                          \
            const int node_ = (gBase) + j_ * 16 + mr;                             \
            bf16x8 f_ = {};                                                       \
            bf16x8 g_ = {};                                                       \
            if (node_ < NUM_NODES) {                                              \
                const floatx4* hp_ =                                              \
                    (const floatx4*)(h_node + (size_t)node_ * 32 + q * 8);        \
                floatx4 v0_ = hp_[0], v1_ = hp_[1];                               \
                f_[0] = (bf16)v0_[0]; f_[1] = (bf16)v0_[1];                       \
                f_[2] = (bf16)v0_[2]; f_[3] = (bf16)v0_[3];                       \
                f_[4] = (bf16)v1_[0]; f_[5] = (bf16)v1_[1];                       \
                f_[6] = (bf16)v1_[2]; f_[7] = (bf16)v1_[3];                       \
                if (q == 0) {                                                     \
                    const float* xp_ = x + (size_t)node_ * 5;                     \
                    g_[0] = (bf16)xp_[0]; g_[1] = (bf16)xp_[1];                   \
                    g_[2] = (bf16)xp_[2]; g_[3] = (bf16)xp_[3];                   \
                    g_[4] = (bf16)xp_[4];                                         \
                    g_[5] = (bf16)1.0f;   /* bias-1 slot (k=37) */                \
                }                                                                 \
            }                                                                     \
            A0[j_] = f_;                                                          \
            A1[j_] = g_;                                                          \
        }                                                                         \
    } while (0)

// Persistent-chunk kernel; per-wave-private LDS, no __syncthreads.
// Phase-C outputs stay in registers; the segment sum is a masked register add
// per group + deferred cross-lane flush (4x shfl_xor over the mr bits +
// atomicAdd from lanes mr==0) only when the segment changes. Removes the fp32
// LDS writes and the ~32-iteration serial LDS walk per group.
__global__ __launch_bounds__(256, 2)
void dag_mfma_kernel(const float* __restrict__ h_node,
                     const float* __restrict__ x,
                     const float* __restrict__ W1, const float* __restrict__ b1,
                     const float* __restrict__ W2, const float* __restrict__ b2,
                     const float* __restrict__ W3, const float* __restrict__ b3,
                     const int* __restrict__ ptr,
                     float* __restrict__ out) {
    __shared__ __align__(16) char sBuf[16 * TILE_BYTES];   // 36,864 B (4 waves)

    const int tid = threadIdx.x;
    const int w   = tid >> 6;
    const int l   = tid & 63;
    const int q   = l >> 4;
    const int mr  = l & 15;

    const int wStart = blockIdx.x * CHUNK + w * WCHUNK;
    if (wStart >= NUM_NODES) return;          // safe: no barriers in this kernel

    const int pstride = (ptr[NUM_DAGS] == NUM_NODES) ? 1 : 2;

    // ---- issue group-0 activation loads first (start HBM fetch early) ----
    bf16x8 a0c[4], a1c[4];
    bf16x8 a0n[4] = {}, a1n[4] = {};
    LOADG(wStart, a0c, a1c);

    // ---- weight A-fragments (once per block; L2-resident) ----
    bf16x8 w1f[2][4], w2f[2][4], w3f[2][2];
    #pragma unroll
    for (int s = 0; s < 2; ++s) {
        #pragma unroll
        for (int mt = 0; mt < 4; ++mt) {
            #pragma unroll
            for (int j = 0; j < 8; ++j) {
                const int kk  = s * 32 + q * 8 + j;
                const int col = mt * 16 + mr;
                float v1;
                if      (kk < 32)  v1 = W1[(kk + 5) * 64 + col];
                else if (kk < 37)  v1 = W1[(kk - 32) * 64 + col];
                else if (kk == 37) v1 = b1[col];
                else               v1 = 0.0f;
                w1f[s][mt][j] = (bf16)v1;
                w2f[s][mt][j] = (bf16)W2[kk * 64 + col];
                if (mt < 2) w3f[s][mt][j] = (bf16)W3[kk * 32 + mt * 16 + mr];
            }
        }
    }
    floatx4 b2f[4], b3f[2];
    #pragma unroll
    for (int mt = 0; mt < 4; ++mt)
        b2f[mt] = *(const floatx4*)(b2 + mt * 16 + q * 4);
    b3f[0] = *(const floatx4*)(b3 + q * 4);
    b3f[1] = *(const floatx4*)(b3 + 16 + q * 4);

    // one binary search per wave; tracked incrementally afterwards
    int seg = seg_of(ptr, wStart, pstride);

    // running per-lane partial sums for the currently-open segment
    int accSeg = seg;
    floatx4 accLo = {}, accHi = {};

    char* myBuf = sBuf + w * WAVE_LDS;

    for (int g = 0; g < NGROUPS; ++g) {
        const int gLo = wStart + g * 64;
        if (gLo >= NUM_NODES) break;

        // prefetch next group's activations (hidden under the MFMA phases)
        if (g + 1 < NGROUPS) LOADG(gLo + 64, a0n, a1n);

        // ---- phase A: layer 1 (reg frags -> relu -> LDS) ----
        #pragma unroll
        for (int j = 0; j < 4; ++j) {
            floatx4 c[4] = {};
            #pragma unroll
            for (int mt = 0; mt < 4; ++mt) {
                c[mt] = MFMA(w1f[0][mt], a0c[j], c[mt]);
                c[mt] = MFMA(w1f[1][mt], a1c[j], c[mt]);
            }
            char* tb = myBuf + j * TILE_BYTES + mr * ROW_BYTES;
            #pragma unroll
            for (int mt = 0; mt < 4; ++mt) {
                bf16x4 v;
                v[0] = (bf16)fmaxf(c[mt][0], 0.0f);
                v[1] = (bf16)fmaxf(c[mt][1], 0.0f);
                v[2] = (bf16)fmaxf(c[mt][2], 0.0f);
                v[3] = (bf16)fmaxf(c[mt][3], 0.0f);
                *(bf16x4*)(tb + mt * 32 + q * 8) = v;   // feats mt*16+q*4.. of node mr
            }
        }

        // ---- phase B: layer 2 (LDS -> relu -> LDS in place; DS in-order/wave) ----
        #pragma unroll
        for (int j = 0; j < 4; ++j) {
            char* tb = myBuf + j * TILE_BYTES + mr * ROW_BYTES;
            bf16x8 h0 = *(const bf16x8*)(tb + q * 16);        // feats q*8..+7
            bf16x8 h1 = *(const bf16x8*)(tb + 64 + q * 16);   // feats 32+q*8..+7
            floatx4 c[4];
            #pragma unroll
            for (int mt = 0; mt < 4; ++mt) {
                c[mt] = b2f[mt];
                c[mt] = MFMA(w2f[0][mt], h0, c[mt]);
                c[mt] = MFMA(w2f[1][mt], h1, c[mt]);
            }
            #pragma unroll
            for (int mt = 0; mt < 4; ++mt) {
                bf16x4 v;
                v[0] = (bf16)fmaxf(c[mt][0], 0.0f);
                v[1] = (bf16)fmaxf(c[mt][1], 0.0f);
                v[2] = (bf16)fmaxf(c[mt][2], 0.0f);
                v[3] = (bf16)fmaxf(c[mt][3], 0.0f);
                *(bf16x4*)(tb + mt * 32 + q * 8) = v;
            }
        }

        // ---- phase C: layer 3 (LDS -> fp32 in REGISTERS) ----
        // D layout: lane (q,mr) holds feats q*4+r (dLo) and 16+q*4+r (dHi)
        // of node gLo + j*16 + mr.
        floatx4 dLo[4], dHi[4];
        #pragma unroll
        for (int j = 0; j < 4; ++j) {
            char* tb = myBuf + j * TILE_BYTES + mr * ROW_BYTES;
            bf16x8 p0 = *(const bf16x8*)(tb + q * 16);
            bf16x8 p1 = *(const bf16x8*)(tb + 64 + q * 16);
            floatx4 d0 = b3f[0], d1 = b3f[1];
            d0 = MFMA(w3f[0][0], p0, d0);
            d0 = MFMA(w3f[1][0], p1, d0);
            d1 = MFMA(w3f[0][1], p0, d1);
            d1 = MFMA(w3f[1][1], p1, d1);
            dLo[j] = d0; dHi[j] = d1;
        }

        // ---- epilogue: register-space segment sum with deferred flush ----
        {
            const int gEnd = (gLo + 64 < NUM_NODES) ? gLo + 64 : NUM_NODES;
            while (ptr[(seg + 1) * pstride] <= gLo) ++seg;
            int segLast = seg;
            while (ptr[(segLast + 1) * pstride] <= gEnd - 1) ++segLast;

            const bool fullOne = (seg == segLast) && (gEnd == gLo + 64);

            for (int s = seg; s <= segLast; ++s) {
                floatx4 pLo, pHi;
                if (fullOne) {
                    // whole 64-node group inside one segment: unmasked sum
                    pLo = dLo[0] + dLo[1] + dLo[2] + dLo[3];
                    pHi = dHi[0] + dHi[1] + dHi[2] + dHi[3];
                } else {
                    int lo = ptr[s * pstride];
                    int hi = ptr[(s + 1) * pstride];
                    if (hi > gEnd) hi = gEnd;
                    if (hi <= lo) continue;         // empty segment
                    pLo = (floatx4){0.f, 0.f, 0.f, 0.f};
                    pHi = (floatx4){0.f, 0.f, 0.f, 0.f};
                    #pragma unroll
                    for (int j = 0; j < 4; ++j) {
                        const int node = gLo + j * 16 + mr;
                        if (node >= lo && node < hi) { pLo += dLo[j]; pHi += dHi[j]; }
                    }
                }
                if (s == accSeg) {
                    accLo += pLo; accHi += pHi;
                } else {
                    // flush accSeg: reduce over mr bits, atomic from mr==0 lanes
                    #pragma unroll
                    for (int m = 1; m <= 8; m <<= 1) {
                        #pragma unroll
                        for (int r = 0; r < 4; ++r) {
                            accLo[r] += __shfl_xor(accLo[r], m, 64);
                            accHi[r] += __shfl_xor(accHi[r], m, 64);
                        }
                    }
                    if (mr == 0) {
                        #pragma unroll
                        for (int r = 0; r < 4; ++r) {
                            atomicAdd(&out[accSeg * NE + q * 4 + r],      accLo[r]);
                            atomicAdd(&out[accSeg * NE + 16 + q * 4 + r], accHi[r]);
                        }
                    }
                    accLo = pLo; accHi = pHi; accSeg = s;
                }
            }
            seg = segLast;
        }

        // rotate prefetch buffers (static indices; becomes register renames)
        #pragma unroll
        for (int j = 0; j < 4; ++j) { a0c[j] = a0n[j]; a1c[j] = a1n[j]; }
    }

    // ---- final flush of the open segment ----
    {
        #pragma unroll
        for (int m = 1; m <= 8; m <<= 1) {
            #pragma unroll
            for (int r = 0; r < 4; ++r) {
                accLo[r] += __shfl_xor(accLo[r], m, 64);
                accHi[r] += __shfl_xor(accHi[r], m, 64);
            }
        }
        if (mr == 0) {
            #pragma unroll
            for (int r = 0; r < 4; ++r) {
                atomicAdd(&out[accSeg * NE + q * 4 + r],      accLo[r]);
                atomicAdd(&out[accSeg * NE + 16 + q * 4 + r], accHi[r]);
            }
        }
    }
}

extern "C" void kernel_launch(void* const* d_in, const int* in_sizes, int n_in,
                              void* d_out, int out_size, void* d_ws, size_t ws_size,
                              hipStream_t stream) {
    const float* h_node = (const float*)d_in[0];
    const float* x      = (const float*)d_in[1];
    const float* W1     = (const float*)d_in[2];
    const float* b1     = (const float*)d_in[3];
    const float* W2     = (const float*)d_in[4];
    const float* b2     = (const float*)d_in[5];
    const float* W3     = (const float*)d_in[6];
    const float* b3     = (const float*)d_in[7];
    const int*   ptr    = (const int*)d_in[8];
    float* out          = (float*)d_out;

    hipMemsetAsync(out, 0, (size_t)out_size * sizeof(float), stream);

    const int grid = (NUM_NODES + CHUNK - 1) / CHUNK;   // 977 blocks, 2048 nodes each
    dag_mfma_kernel<<<grid, 256, 0, stream>>>(h_node, x, W1, b1, W2, b2,
                                              W3, b3, ptr, out);
}